// Round 4
// baseline (252.114 us; speedup 1.0000x reference)
//
#include <hip/hip_runtime.h>

#define SEG 256
#define SMOOTH_K 9
#define BASE_AMP 0.08f
#define L 4096
#define ROW (2 * L)          // floats per batch row (8192)

// ---------------------------------------------------------------------------
// K1: effective pattern -> ws[0..511]  ([2][256])
// ---------------------------------------------------------------------------
__global__ __launch_bounds__(256) void pattern_kernel(
    const float* __restrict__ pi, const float* __restrict__ pq,
    float* __restrict__ pat_out) {
    __shared__ float wsum0[4], wsum1[4], wsq[4];

    const int i = threadIdx.x;            // 0..255 (position)
    float v0 = 0.f, v1 = 0.f;
    #pragma unroll
    for (int j = -(SMOOTH_K / 2); j <= SMOOTH_K / 2; ++j) {
        int k = i + j;
        if (k >= 0 && k < SEG) { v0 += pi[k]; v1 += pq[k]; }
    }
    v0 *= (1.0f / SMOOTH_K);
    v1 *= (1.0f / SMOOTH_K);

    float s0 = v0, s1 = v1;
    #pragma unroll
    for (int off = 32; off; off >>= 1) {
        s0 += __shfl_down(s0, off);
        s1 += __shfl_down(s1, off);
    }
    const int wid = i >> 6, lane = i & 63;
    if (lane == 0) { wsum0[wid] = s0; wsum1[wid] = s1; }
    __syncthreads();
    const float m0 = (wsum0[0] + wsum0[1] + wsum0[2] + wsum0[3]) * (1.0f / SEG);
    const float m1 = (wsum1[0] + wsum1[1] + wsum1[2] + wsum1[3]) * (1.0f / SEG);
    const float d0 = v0 - m0;
    const float d1 = v1 - m1;

    float q = d0 * d0 + d1 * d1;
    #pragma unroll
    for (int off = 32; off; off >>= 1) q += __shfl_down(q, off);
    if (lane == 0) wsq[wid] = q;
    __syncthreads();
    const float msq = (wsq[0] + wsq[1] + wsq[2] + wsq[3]) * (1.0f / (2 * SEG));
    const float scale = BASE_AMP / sqrtf(msq + 1e-8f);

    pat_out[i]       = d0 * scale;
    pat_out[SEG + i] = d1 * scale;
}

// ---------------------------------------------------------------------------
// K2: per-row amplitude -> amp[b].  Pure read stream + block reduce.
// ---------------------------------------------------------------------------
__global__ __launch_bounds__(256) void amp_kernel(
    const float* __restrict__ x, float* __restrict__ amp) {
    const int b = blockIdx.x;
    const int t = threadIdx.x;
    const float4* __restrict__ xr =
        reinterpret_cast<const float4*>(x + (size_t)b * ROW);

    __shared__ float wred[4];

    float4 v[8];
    #pragma unroll
    for (int k = 0; k < 8; ++k) v[k] = xr[t + k * 256];

    float ssq = 0.f;
    #pragma unroll
    for (int k = 0; k < 8; ++k)
        ssq += v[k].x * v[k].x + v[k].y * v[k].y + v[k].z * v[k].z +
               v[k].w * v[k].w;

    #pragma unroll
    for (int off = 32; off; off >>= 1) ssq += __shfl_down(ssq, off);
    if ((t & 63) == 0) wred[t >> 6] = ssq;
    __syncthreads();
    if (t == 0) {
        const float tot = wred[0] + wred[1] + wred[2] + wred[3];
        amp[b] = sqrtf(tot * (1.0f / ROW) + 1e-12f);
    }
}

// ---------------------------------------------------------------------------
// K3: branch-free streaming apply:  out = x + amp[b] * pat_padded[clamp(r)]
// Zero-padded pattern in LDS; min/max clamp maps out-of-segment lanes to the
// zero slots. No reduction, no store-after-barrier, stores flow freely.
// ---------------------------------------------------------------------------
__global__ __launch_bounds__(256) void add_kernel(
    const float* __restrict__ x, const int* __restrict__ starts,
    const float* __restrict__ amp, const float* __restrict__ pat,
    float* __restrict__ out) {
    const int b = blockIdx.x;
    const int t = threadIdx.x;

    const float4* __restrict__ xr =
        reinterpret_cast<const float4*>(x + (size_t)b * ROW);
    float4* __restrict__ outr = reinterpret_cast<float4*>(out + (size_t)b * ROW);

    __shared__ float sp[2][SEG + 2];   // sp[c][0] = sp[c][SEG+1] = 0
    sp[0][1 + t] = pat[t];
    sp[1][1 + t] = pat[SEG + t];
    if (t == 0) {
        sp[0][0] = 0.f; sp[0][SEG + 1] = 0.f;
        sp[1][0] = 0.f; sp[1][SEG + 1] = 0.f;
    }
    const int   s = starts[b];
    const float a = amp[b];
    __syncthreads();

    #pragma unroll
    for (int k = 0; k < 8; ++k) {
        const int idx = t + k * 256;          // float4 index within row
        float4 v = xr[idx];
        const int c = idx >> 10;              // channel
        const int r = ((idx & 1023) << 2) - s;  // rel pos of .x in segment
        const float* __restrict__ pc = sp[c];
        const int i0 = min(max(r,     -1), SEG) + 1;
        const int i1 = min(max(r + 1, -1), SEG) + 1;
        const int i2 = min(max(r + 2, -1), SEG) + 1;
        const int i3 = min(max(r + 3, -1), SEG) + 1;
        v.x += a * pc[i0];
        v.y += a * pc[i1];
        v.z += a * pc[i2];
        v.w += a * pc[i3];
        outr[idx] = v;
    }
}

// ---------------------------------------------------------------------------
extern "C" void kernel_launch(void* const* d_in, const int* in_sizes, int n_in,
                              void* d_out, int out_size, void* d_ws,
                              size_t ws_size, hipStream_t stream) {
    const float* x      = (const float*)d_in[0];
    const float* pi     = (const float*)d_in[1];
    const float* pq     = (const float*)d_in[2];
    const int*   starts = (const int*)d_in[3];
    float* out = (float*)d_out;
    float* pat = (float*)d_ws;                 // 512 floats
    float* amp = (float*)d_ws + 512;           // 4096 floats

    const int B = in_sizes[0] / ROW;           // 4096

    pattern_kernel<<<1, 256, 0, stream>>>(pi, pq, pat);
    amp_kernel<<<B, 256, 0, stream>>>(x, amp);
    add_kernel<<<B, 256, 0, stream>>>(x, starts, amp, pat, out);
}